// Round 25
// baseline (129.958 us; speedup 1.0000x reference)
//
#include <hip/hip_runtime.h>
#include <hip/hip_bf16.h>
#include <stdint.h>
#include <math.h>

typedef __bf16 bf16;
typedef __bf16 bf16x8 __attribute__((ext_vector_type(8)));
typedef float f32x4 __attribute__((ext_vector_type(4)));
typedef short s4 __attribute__((ext_vector_type(4)));  // 4 bf16 (2 VGPR)

#define QSCALE 0.1803368801111f  /* 0.125 * log2(e) */

// B=8, N=1025 (32*32+1), DIM=512, HEADS=12, DH=64, INNER=768
// M = 8*1025 = 8200, padded to 8320. KV per (b,h): 1025 = 16*64 + 1 -> 16 full
// tiles + rank-1 tail (kv=1024) handled in-register.
// V layout "vP": per head [kvq=272][d=64][e=4], kv = kvq*4+e.
// PV uses mfma_f32_16x16x16_bf16 whose A-fragment (lane: A[l15][4*l4+e])
// exactly matches the swapped-QK^T P ownership; no cross-lane P movement.
// Softmax: shift-free (scores exp2-domain max ~8.3 -> p<=~300, FP-safe).
// ROUND-16: V must come from LDS. ROUND-18: ones-MFMA denominator loses.
// ROUND-19/20: flash was wave-limited; 8-wave blocks fixed it.
// ROUND-24: gemm0 scatter fixed via LDS round-trip epilogue (coalesced 8B).
// ROUND-25: conv 4-row y-blocking (x reads 75MB->37MB); gemm1 -> 8 waves
// (was 8 waves/CU, the wave-starvation signature) with B staged by waves<4
// and wave-uniform divergent vmcnt.

__device__ __forceinline__ void gload_lds16(const void* g, void* l) {
  typedef const __attribute__((address_space(1))) char g_char;
  typedef __attribute__((address_space(3))) char l_char;
  g_char* gp = (g_char*)(uintptr_t)g;
  l_char* lp = (l_char*)(uint32_t)(uintptr_t)l;
  __builtin_amdgcn_global_load_lds(gp, lp, 16, 0, 0);
}

__device__ __forceinline__ float fexp2(float x) {
#if __has_builtin(__builtin_amdgcn_exp2f)
  return __builtin_amdgcn_exp2f(x);
#else
  return exp2f(x);
#endif
}

__device__ __forceinline__ float frcp(float x) {
#if __has_builtin(__builtin_amdgcn_rcpf)
  return __builtin_amdgcn_rcpf(x);
#else
  return 1.f / x;
#endif
}

__device__ __forceinline__ uint32_t pk2(float a, float b) {
  union { bf16 h; unsigned short u; } ua, ub;
  ua.h = (bf16)a; ub.h = (bf16)b;
  return (uint32_t)ua.u | ((uint32_t)ub.u << 16);
}

__device__ __forceinline__ f32x4 pv_mfma(s4 a, s4 b, f32x4 c) {
#if __has_builtin(__builtin_amdgcn_mfma_f32_16x16x16bf16_1k)
  return __builtin_amdgcn_mfma_f32_16x16x16bf16_1k(a, b, c, 0, 0, 0);
#else
  asm volatile("v_mfma_f32_16x16x16_bf16 %0, %1, %2, %0" : "+v"(c) : "v"(a), "v"(b));
  return c;
#endif
}

// FUSED prep + depthwise conv. Blocks [0,2848): vec8 convert — x->xb (pad to
// 8320 rows), w_qkv->bf16, w_out->bf16. 8-elem-unit boundaries: xb 532480
// (src valid 524800), wqkv 147456, wout 49152; total 729088 = 2848*256.
// Blocks [2848,3360): 3x3 depthwise conv (SAME), 4 OUTPUT ROWS x 4 cols per
// block (6 loaded rows shared by 4 outputs -> ~2x fewer x reads) + cls
// passthrough -> locb (B,1025,512) bf16, no RMW (added in k_flash).
__global__ __launch_bounds__(256) void k_prep(const float* __restrict__ x,
                                              const float* __restrict__ wqkv,
                                              const float* __restrict__ wout,
                                              bf16* __restrict__ xb, bf16* __restrict__ wqkvb,
                                              bf16* __restrict__ woutb,
                                              const float* __restrict__ wdw,
                                              bf16* __restrict__ locb) {
  if (blockIdx.x >= 2848) {
    const int lb = blockIdx.x - 2848;          // 0..511
    const int b = lb >> 6;                     // 8 batches
    const int yseg = (lb >> 3) & 7;            // 8 y segments of 4 rows
    const int xseg = lb & 7;                   // 8 x segments of 4 cols
    const int c = threadIdx.x * 2;             // channels c, c+1
    const int x0 = xseg * 4, y0 = yseg * 4;
    float wa[9], wb[9];
#pragma unroll
    for (int k = 0; k < 9; ++k) {
      wa[k] = wdw[(size_t)c * 9 + k];
      wb[k] = wdw[(size_t)(c + 1) * 9 + k];
    }
    const float* xrow = x + ((size_t)b * 1025 + 1) * 512 + c;
    float A0[4] = {}, B0[4] = {}, A1[4] = {}, B1[4] = {};
    for (int cc = x0 - 1; cc <= x0 + 4; ++cc) {
      const bool cok = (cc >= 0 && cc < 32);
      float2 v[6];
#pragma unroll
      for (int i = 0; i < 6; ++i) {
        int ry = y0 - 1 + i;
        v[i] = (cok && ry >= 0 && ry <= 31)
                   ? *(const float2*)&xrow[((size_t)ry * 32 + cc) * 512]
                   : make_float2(0.f, 0.f);
      }
      int oc = cc - 1;
      bool wok = (oc >= x0 && oc <= x0 + 3);
#pragma unroll
      for (int j = 0; j < 4; ++j) {
        float t0a = v[j].x * wa[0] + v[j + 1].x * wa[3] + v[j + 2].x * wa[6];
        float t1a = v[j].x * wa[1] + v[j + 1].x * wa[4] + v[j + 2].x * wa[7];
        float t2a = v[j].x * wa[2] + v[j + 1].x * wa[5] + v[j + 2].x * wa[8];
        float t0b = v[j].y * wb[0] + v[j + 1].y * wb[3] + v[j + 2].y * wb[6];
        float t1b = v[j].y * wb[1] + v[j + 1].y * wb[4] + v[j + 2].y * wb[7];
        float t2b = v[j].y * wb[2] + v[j + 1].y * wb[5] + v[j + 2].y * wb[8];
        if (wok) {
          size_t o = ((size_t)b * 1025 + 1 + (y0 + j) * 32 + oc) * 512 + c;
          *(uint32_t*)&locb[o] = pk2(A0[j] + t2a, A1[j] + t2b);
        }
        A0[j] = B0[j] + t1a; B0[j] = t0a;
        A1[j] = B1[j] + t1b; B1[j] = t0b;
      }
    }
    if (yseg == 0 && xseg == 0) {
      float2 xc = *(const float2*)&x[((size_t)b * 1025) * 512 + c];
      *(uint32_t*)&locb[((size_t)b * 1025) * 512 + c] = pk2(xc.x, xc.y);
    }
    return;
  }
  // ---- vec8 prep branch (u = 8-elem unit index)
  int u = blockIdx.x * 256 + threadIdx.x;
  const float* src = nullptr;
  bf16* dst = nullptr;
  bool zero = false;
  if (u < 532480) {
    if (u >= 524800) zero = true;
    src = x; dst = xb;
  } else if (u < 679936) {
    u -= 532480; src = wqkv; dst = wqkvb;
  } else {
    u -= 679936; src = wout; dst = woutb;
  }
  float4 a = make_float4(0.f, 0.f, 0.f, 0.f), bq = a;
  if (!zero) {
    a  = *(const float4*)&src[(size_t)u * 8];
    bq = *(const float4*)&src[(size_t)u * 8 + 4];
  }
  uint4 p;
  p.x = pk2(a.x, a.y);
  p.y = pk2(a.z, a.w);
  p.z = pk2(bq.x, bq.y);
  p.w = pk2(bq.z, bq.w);
  *(uint4*)&dst[(size_t)u * 8] = p;
}

// Tiled bf16 GEMM, 3-STAGE pipeline (T3+T4): BK=32, triple-buffered LDS,
// counted vmcnt -> prefetch distance 2. Chunk swizzle (row>>1)&3.
// Bijective XCD-chunked 1D grid (m204). 8 waves (2x4 wave grid).
// If BN/16 < NWAVE, B is staged by waves w < BN/16 only; the vmcnt count is
// then per-wave (wave-uniform divergence -> legal).
// EPI=0 (128x128, NTN=18): q/k blocks (tn<12) use the COALESCED LDS
//   round-trip epilogue; vP blocks (tn>=12) keep the scattered path.
// EPI=1 (128x64, NTN=8): +bias, fp32 out, row<8200. Grid 520, 8 waves.
template <int EPI, int BM, int BN, int NTN, int TPB>
__global__ __launch_bounds__(TPB) void k_gemm(const bf16* __restrict__ A,
                                              const bf16* __restrict__ Bt, int K,
                                              bf16* __restrict__ q, bf16* __restrict__ kk,
                                              bf16* __restrict__ vt,
                                              const float* __restrict__ bias,
                                              float* __restrict__ out) {
  __shared__ __attribute__((aligned(16))) bf16 smem[3 * (BM + BN) * 32];
  constexpr int NWAVE = TPB / 64;
  constexpr int WCN = (NWAVE == 8) ? 4 : 2;   // wave-grid cols
  constexpr int WRN = NWAVE / WCN;            // wave-grid rows (=2)
  constexpr int WROWS = BM / WRN, WCOLS = BN / WCN;
  constexpr int MF = WROWS / 16, NF = WCOLS / 16;
  constexpr int AL = BM / 16 / NWAVE;         // A wave-loads per stage
  constexpr int BBLK = BN / 16;               // B 16-row blocks per stage
  constexpr bool BSPLIT = (BBLK < NWAVE);     // B staged by waves < BBLK
  constexpr int BL = BSPLIT ? 1 : (BBLK / NWAVE);
  const int tid = threadIdx.x;
  const int lane = tid & 63;
  const int w = tid >> 6;
  const int wr = w / WCN, wc = w % WCN;
  const int l15 = lane & 15, l4 = lane >> 4;

  auto sAb = [&](int bi) { return smem + bi * (BM * 32); };
  auto sBb = [&](int bi) { return smem + 3 * BM * 32 + bi * (BN * 32); };

  const int nwg = gridDim.x;
  const int qq = nwg >> 3, rr = nwg & 7;
  const int xcd = blockIdx.x & 7, idx = blockIdx.x >> 3;
  const int logical = (xcd < rr) ? xcd * (qq + 1) + idx
                                 : rr * (qq + 1) + (xcd - rr) * qq + idx;
  const int tm = logical / NTN, tn = logical - tm * NTN;

  f32x4 acc[MF][NF] = {};

  const int srow = lane >> 2, schunk = lane & 3;
  const int rA = w * (AL * 16) + srow;
  const bf16* aS = A + ((size_t)(tm * BM + rA)) * K + ((schunk ^ ((rA >> 1) & 3)) * 8);
  const int rB = (BSPLIT ? w * 16 : w * (BL * 16)) + srow;
  const bf16* bS = Bt + ((size_t)(tn * BN + rB)) * K + ((schunk ^ ((rB >> 1) & 3)) * 8);

  auto STAGE = [&](int bi, int kt) {
    size_t o = (size_t)kt * 32;
#pragma unroll
    for (int i = 0; i < AL; ++i)
      gload_lds16(aS + (size_t)i * 16 * K + o, &sAb(bi)[(w * (AL * 16) + i * 16) * 32]);
    if constexpr (BSPLIT) {
      if (w < BBLK) gload_lds16(bS + o, &sBb(bi)[(w * 16) * 32]);
    } else {
#pragma unroll
      for (int i = 0; i < BL; ++i)
        gload_lds16(bS + (size_t)i * 16 * K + o, &sBb(bi)[(w * (BL * 16) + i * 16) * 32]);
    }
  };

  STAGE(0, 0);
  STAGE(1, 1);
  int cur = 0;
  const int Ksteps = K >> 5;
  for (int kt = 0; kt < Ksteps; ++kt) {
    if (kt + 1 < Ksteps) {
      if constexpr (BSPLIT) {
        // per-wave in-flight count (wave-uniform branch: w uniform in wave)
        if (w < BBLK) asm volatile("s_waitcnt vmcnt(2)" ::: "memory");
        else          asm volatile("s_waitcnt vmcnt(1)" ::: "memory");
      } else {
        constexpr int LOADS = AL + BL;
        if constexpr (LOADS == 4)      asm volatile("s_waitcnt vmcnt(4)" ::: "memory");
        else if constexpr (LOADS == 3) asm volatile("s_waitcnt vmcnt(3)" ::: "memory");
        else                           asm volatile("s_waitcnt vmcnt(2)" ::: "memory");
      }
    } else {
      asm volatile("s_waitcnt vmcnt(0)" ::: "memory");
    }
    __builtin_amdgcn_s_barrier();
    __builtin_amdgcn_sched_barrier(0);
    if (kt + 2 < Ksteps) {
      int b2 = cur + 2; if (b2 >= 3) b2 -= 3;
      STAGE(b2, kt + 2);
    }

    const bf16* a_ = sAb(cur);
    const bf16* b_ = sBb(cur);
    bf16x8 af[MF], bfr[NF];
#pragma unroll
    for (int mf = 0; mf < MF; ++mf) {
      int row = wr * WROWS + mf * 16 + l15;
      int phys = l4 ^ ((row >> 1) & 3);
      af[mf] = *(const bf16x8*)&a_[row * 32 + phys * 8];
    }
#pragma unroll
    for (int nf = 0; nf < NF; ++nf) {
      int row = wc * WCOLS + nf * 16 + l15;
      int phys = l4 ^ ((row >> 1) & 3);
      bfr[nf] = *(const bf16x8*)&b_[row * 32 + phys * 8];
    }
    __builtin_amdgcn_s_setprio(1);
#pragma unroll
    for (int mf = 0; mf < MF; ++mf)
#pragma unroll
      for (int nf = 0; nf < NF; ++nf)
        acc[mf][nf] =
            __builtin_amdgcn_mfma_f32_16x16x32_bf16(bfr[nf], af[mf], acc[mf][nf], 0, 0, 0);
    __builtin_amdgcn_s_setprio(0);
    ++cur; if (cur >= 3) cur = 0;
  }

  const int RbaseL = tm * BM + wr * WROWS + l15;
  const int CbaseL = tn * BN + wc * WCOLS + l4 * 4;

  if (EPI == 0 && tn < 12) {
    // ---- coalesced q/k epilogue via LDS round-trip ----
    constexpr int PAD = 132;                  // bf16 elems per row (8B-aligned)
    const int seg = tn / 6;                   // 0 = q, 1 = k (tile fits one seg)
    const float scl = seg ? 1.f : QSCALE;
    bf16* ct = smem;                          // [BM][PAD] C-tile
    __syncthreads();                          // K-loop LDS dead everywhere
#pragma unroll
    for (int mf = 0; mf < MF; ++mf) {
      int rl = wr * WROWS + mf * 16 + l15;
#pragma unroll
      for (int nf = 0; nf < NF; ++nf) {
        int cl = wc * WCOLS + nf * 16 + l4 * 4;
        uint2 p;
        p.x = pk2(acc[mf][nf][0] * scl, acc[mf][nf][1] * scl);
        p.y = pk2(acc[mf][nf][2] * scl, acc[mf][nf][3] * scl);
        *(uint2*)&ct[rl * PAD + cl] = p;
      }
    }
    __syncthreads();
    bf16* dst = seg ? kk : q;
    const int h0 = tn * 2 - seg * 12;         // first of the 2 heads in tile
#pragma unroll
    for (int it = 0; it < BM * 32 / TPB; ++it) {
      int u = it * TPB + tid;                 // 8B unit: 32 per row
      int row = u >> 5;
      int R = tm * BM + row;
      if (R >= 8200) continue;
      int b = R / 1025, n = R - b * 1025;     // per-row -> straddle-safe
      int hh = (u >> 4) & 1;
      int d0 = (u & 15) * 4;
      uint2 v = *(const uint2*)&ct[row * PAD + hh * 64 + d0];
      *(uint2*)&dst[(((size_t)b * 12 + h0 + hh) * 1088 + n) * 64 + d0] = v;
    }
    return;
  }

#pragma unroll
  for (int mf = 0; mf < MF; ++mf) {
    int R = RbaseL + mf * 16;
    if (R >= 8200) continue;
    if (EPI == 0) {
      int b = R / 1025;
      int n = R - b * 1025;
      int kvq = n >> 2, e = n & 3;
#pragma unroll
      for (int nf = 0; nf < NF; ++nf) {
        int Cc0 = CbaseL + nf * 16;
        int inner = Cc0 - 1536;               // tn>=12 -> seg 2 (vP) only
        int h = inner >> 6, d0 = inner & 63;
        bf16* vb = &vt[(((size_t)(b * 12 + h) * 272 + kvq) * 64 + d0) * 4 + e];
#pragma unroll
        for (int r = 0; r < 4; ++r) vb[r * 4] = (bf16)acc[mf][nf][r];
      }
    } else {
#pragma unroll
      for (int nf = 0; nf < NF; ++nf) {
        int Cc0 = CbaseL + nf * 16;
        float4 bz = *(const float4*)&bias[Cc0];
        float4 o4;
        o4.x = acc[mf][nf][0] + bz.x;
        o4.y = acc[mf][nf][1] + bz.y;
        o4.z = acc[mf][nf][2] + bz.z;
        o4.w = acc[mf][nf][3] + bz.w;
        *(float4*)&out[(size_t)R * 512 + Cc0] = o4;
      }
    }
  }
}

// Flash attention, swapped-QK^T, double-buffered K/V, shift-free softmax.
// 8 WAVES per block (512 thr), 128 q-rows/block, grid 864 (= 8*108, exact
// XCD-bijective): 4 blocks/CU x 8 waves = 32 waves/CU, single dispatch round.
// 16 full KV tiles + rank-1 tail. PV via mfma_16x16x16 (P in-register).
// Epilogue fuses the depthwise-conv local branch: adds locb for heads h<8.
// LDS = 32768 B. NOTE: no min-waves launch_bounds (round-4 spill lesson).
__global__ __launch_bounds__(512) void k_flash(const bf16* __restrict__ qg,
                                               const bf16* __restrict__ kg,
                                               const bf16* __restrict__ vpg,
                                               const bf16* __restrict__ locb,
                                               bf16* __restrict__ outb) {
  __shared__ __attribute__((aligned(16))) bf16 sK[2][64 * 64];
  __shared__ __attribute__((aligned(16))) bf16 sVP[2][16 * 256];  // 16 kvq x 64 d x 4 e
  const int tid = threadIdx.x, lane = tid & 63, w = tid >> 6;  // w = 0..7
  const int l15 = lane & 15, l4 = lane >> 4;
  // XCD-contiguous mapping: 864 = 8 * 108
  const int wg = blockIdx.x;
  const int logical = (wg & 7) * 108 + (wg >> 3);
  const int bh = logical / 9, qgp = logical - bh * 9;   // 9 q-groups of 128
  const int b = bh / 12, h = bh - b * 12;

  // Q fragments (pre-scaled by QSCALE in the QKV GEMM epilogue)
  size_t qoff = ((size_t)bh * 1088 + qgp * 128 + w * 16 + l15) * 64 + l4 * 8;
  const bf16x8 qf0 = *(const bf16x8*)&qg[qoff];
  const bf16x8 qf1 = *(const bf16x8*)&qg[qoff + 32];

  float lreg = 0.f;  // per-lane partial row sum (reduced in epilogue)
  f32x4 oa[4] = {};

  const int px0 = (l4 ^ (l15 & 7)) * 8;        // K LDS swizzled chunk, ks=0
  const int px1 = ((4 + l4) ^ (l15 & 7)) * 8;  // ks=1

  // Staging: wave w covers K rows [w*8, w*8+8) (1 gload/wave) and V elements
  // [w*512, (w+1)*512) (1 gload/wave). Both tiles advance 4096 elems per t.
  const int rowK = w * 8 + (lane >> 3);
  const int clogK = (lane & 7) ^ (rowK & 7);
  const bf16* kS = kg + ((size_t)bh * 1088 + rowK) * 64 + clogK * 8;
  const bf16* vS = vpg + (size_t)bh * 69632 + w * 512 + lane * 8;
  const int kD = w * 512;   // wave-uniform LDS elem base (lane adds *8)
  const int vD = w * 512;

  auto STAGE = [&](int bi, int t) {
    size_t o = (size_t)t * 4096;
    gload_lds16(kS + o, &sK[bi][kD]);
    gload_lds16(vS + o, &sVP[bi][vD]);
  };

  STAGE(0, 0);
  int cur = 0;

  for (int t = 0; t < 16; ++t) {
    // Wait this tile's loads (issued one full iteration ago), converge. After
    // the barrier all waves consumed buf[cur^1] -> restage is race-free.
    asm volatile("s_waitcnt vmcnt(0)" ::: "memory");
    __builtin_amdgcn_s_barrier();
    __builtin_amdgcn_sched_barrier(0);
    if (t < 15) STAGE(cur ^ 1, t + 1);

    const bf16* kb_ = sK[cur];
    const bf16* vpb = sVP[cur];

    // S^T = K · Q^T : lane holds S[q=l15][kv = jt*16 + l4*4 + r]
    f32x4 sc[4] = {};
    __builtin_amdgcn_s_setprio(1);
#pragma unroll
    for (int jt = 0; jt < 4; ++jt) {
      bf16x8 a0 = *(const bf16x8*)&kb_[(jt * 16 + l15) * 64 + px0];
      sc[jt] = __builtin_amdgcn_mfma_f32_16x16x32_bf16(a0, qf0, sc[jt], 0, 0, 0);
    }
#pragma unroll
    for (int jt = 0; jt < 4; ++jt) {
      bf16x8 a1 = *(const bf16x8*)&kb_[(jt * 16 + l15) * 64 + px1];
      sc[jt] = __builtin_amdgcn_mfma_f32_16x16x32_bf16(a1, qf1, sc[jt], 0, 0, 0);
    }
    __builtin_amdgcn_s_setprio(0);

    // P = exp2(S); pack per-jt into the 16x16x16 A-fragment directly.
    union { uint32_t u[2]; s4 v; } pa[4];
    float lsum = 0.f;
#pragma unroll
    for (int jt = 0; jt < 4; ++jt) {
      float p0 = fexp2(sc[jt][0]);
      float p1 = fexp2(sc[jt][1]);
      float p2 = fexp2(sc[jt][2]);
      float p3 = fexp2(sc[jt][3]);
      lsum += (p0 + p1) + (p2 + p3);
      pa[jt].u[0] = pk2(p0, p1);
      pa[jt].u[1] = pk2(p2, p3);
    }
    lreg += lsum;

    // O += P · V  (16 x mfma_16x16x16, A = in-register P)
    __builtin_amdgcn_s_setprio(1);
#pragma unroll
    for (int jt = 0; jt < 4; ++jt)
#pragma unroll
      for (int db = 0; db < 4; ++db) {
        s4 vf = *(const s4*)&vpb[((jt * 4 + l4) * 64 + db * 16 + l15) * 4];
        oa[db] = pv_mfma(pa[jt].v, vf, oa[db]);
      }
    __builtin_amdgcn_s_setprio(0);
    cur ^= 1;
  }

  // Rank-1 tail: kv = 1024.
  {
    const bf16* k1 = kg + ((size_t)bh * 1088 + 1024) * 64;
    bf16x8 kA = *(const bf16x8*)&k1[l4 * 8];
    bf16x8 kB = *(const bf16x8*)&k1[32 + l4 * 8];
    float s = 0.f;
#pragma unroll
    for (int e = 0; e < 8; ++e)
      s += (float)qf0[e] * (float)kA[e] + (float)qf1[e] * (float)kB[e];
    s += __shfl_xor(s, 16);
    s += __shfl_xor(s, 32);
    float p = fexp2(s);
    if (l4 == 0) lreg += p;  // count once per q-row (epilogue sums l4 copies)
    float pr[4];
#pragma unroll
    for (int r = 0; r < 4; ++r) pr[r] = __shfl(p, l4 * 4 + r);
    const bf16* v1 = vpg + (size_t)bh * 69632 + 65536;  // kvq=256, e=0
#pragma unroll
    for (int db = 0; db < 4; ++db) {
      float vd = (float)v1[(db * 16 + l15) * 4];
#pragma unroll
      for (int r = 0; r < 4; ++r) oa[db][r] += pr[r] * vd;
    }
  }

  float ls = lreg;
  ls += __shfl_xor(ls, 16);
  ls += __shfl_xor(ls, 32);
  float linv = frcp(ls);
#pragma unroll
  for (int r = 0; r < 4; ++r) {
    float ir = __shfl(linv, l4 * 4 + r);
    int n = qgp * 128 + w * 16 + l4 * 4 + r;
    if (n >= 1025) continue;
#pragma unroll
    for (int db = 0; db < 4; ++db) {
      float v = oa[db][r] * ir;
      if (h < 8)
        v += (float)locb[((size_t)b * 1025 + n) * 512 + h * 64 + db * 16 + l15];
      outb[((size_t)b * 1025 + n) * 768 + h * 64 + db * 16 + l15] = (bf16)v;
    }
  }
}

extern "C" void kernel_launch(void* const* d_in, const int* in_sizes, int n_in,
                              void* d_out, int out_size, void* d_ws, size_t ws_size,
                              hipStream_t stream) {
  const float* x = (const float*)d_in[0];
  const float* w_qkv = (const float*)d_in[1];
  const float* w_dw = (const float*)d_in[2];
  const float* w_out = (const float*)d_in[3];
  const float* b_out = (const float*)d_in[4];
  float* out = (float*)d_out;

  char* ws = (char*)d_ws;
  size_t off = 0;
  auto alloc = [&](size_t bytes) {
    char* p = ws + off;
    off = (off + bytes + 255) & ~(size_t)255;
    return p;
  };
  bf16* xb    = (bf16*)alloc((size_t)8320 * 512 * 2);
  bf16* wqkvb = (bf16*)alloc((size_t)2304 * 512 * 2);
  bf16* woutb = (bf16*)alloc((size_t)512 * 768 * 2);
  bf16* qb    = (bf16*)alloc((size_t)96 * 1088 * 64 * 2);
  bf16* kb    = (bf16*)alloc((size_t)96 * 1088 * 64 * 2);
  bf16* vP    = (bf16*)alloc((size_t)96 * 272 * 64 * 4 * 2);  // 69632 elems/head
  bf16* locb  = (bf16*)alloc((size_t)8 * 1025 * 512 * 2);
  bf16* outb  = (bf16*)alloc((size_t)8320 * 768 * 2);

  // Fused prep (vec8: 2848 blocks) + conv (512 blocks, 4-row y-blocking)
  k_prep<<<3360, 256, 0, stream>>>(x, w_qkv, w_out, xb, wqkvb, woutb, w_dw, locb);
  // 1170 = 65*18 blocks (128x128 tiles, 8 waves), XCD-chunked inside kernel
  k_gemm<0, 128, 128, 18, 512><<<1170, 512, 0, stream>>>(xb, wqkvb, 512, qb, kb, vP,
                                                         nullptr, nullptr);
  k_flash<<<864, 512, 0, stream>>>(qb, kb, vP, locb, outb);
  // 520 = 65*8 blocks (128x64 tiles, 8 waves; B staged by waves 0-3)
  k_gemm<1, 128, 64, 8, 512><<<520, 512, 0, stream>>>(outb, woutb, 768, nullptr, nullptr,
                                                      nullptr, b_out, out);
}

// Round 26
// 128.720 us; speedup vs baseline: 1.0096x; 1.0096x over previous
//
#include <hip/hip_runtime.h>
#include <hip/hip_bf16.h>
#include <stdint.h>
#include <math.h>

typedef __bf16 bf16;
typedef __bf16 bf16x8 __attribute__((ext_vector_type(8)));
typedef float f32x4 __attribute__((ext_vector_type(4)));
typedef short s4 __attribute__((ext_vector_type(4)));  // 4 bf16 (2 VGPR)

#define QSCALE 0.1803368801111f  /* 0.125 * log2(e) */

// B=8, N=1025 (32*32+1), DIM=512, HEADS=12, DH=64, INNER=768
// M = 8*1025 = 8200, padded to 8320. KV per (b,h): 1025 = 16*64 + 1 -> 16 full
// tiles + rank-1 tail (kv=1024) handled in-register.
// V layout "vP": per head [kvq=272][d=64][e=4], kv = kvq*4+e.
// PV uses mfma_f32_16x16x16_bf16 whose A-fragment (lane: A[l15][4*l4+e])
// exactly matches the swapped-QK^T P ownership; no cross-lane P movement.
// Softmax: shift-free (scores exp2-domain max ~8.3 -> p<=~300, FP-safe).
// ROUND-16: V must come from LDS. ROUND-18: ones-MFMA denominator loses.
// ROUND-19/20: flash was wave-limited; 8-wave blocks fixed it.
// ROUND-24: gemm0 scatter fixed via LDS round-trip epilogue (coalesced 8B).
// ROUND-25 LESSON: conv y-blocking and gemm1 8-wave/B-split both regressed
// (combined +1.5us) -> reverted to the round-24 best (128.46us).

__device__ __forceinline__ void gload_lds16(const void* g, void* l) {
  typedef const __attribute__((address_space(1))) char g_char;
  typedef __attribute__((address_space(3))) char l_char;
  g_char* gp = (g_char*)(uintptr_t)g;
  l_char* lp = (l_char*)(uint32_t)(uintptr_t)l;
  __builtin_amdgcn_global_load_lds(gp, lp, 16, 0, 0);
}

__device__ __forceinline__ float fexp2(float x) {
#if __has_builtin(__builtin_amdgcn_exp2f)
  return __builtin_amdgcn_exp2f(x);
#else
  return exp2f(x);
#endif
}

__device__ __forceinline__ float frcp(float x) {
#if __has_builtin(__builtin_amdgcn_rcpf)
  return __builtin_amdgcn_rcpf(x);
#else
  return 1.f / x;
#endif
}

__device__ __forceinline__ uint32_t pk2(float a, float b) {
  union { bf16 h; unsigned short u; } ua, ub;
  ua.h = (bf16)a; ub.h = (bf16)b;
  return (uint32_t)ua.u | ((uint32_t)ub.u << 16);
}

__device__ __forceinline__ f32x4 pv_mfma(s4 a, s4 b, f32x4 c) {
#if __has_builtin(__builtin_amdgcn_mfma_f32_16x16x16bf16_1k)
  return __builtin_amdgcn_mfma_f32_16x16x16bf16_1k(a, b, c, 0, 0, 0);
#else
  asm volatile("v_mfma_f32_16x16x16_bf16 %0, %1, %2, %0" : "+v"(c) : "v"(a), "v"(b));
  return c;
#endif
}

// FUSED prep + depthwise conv. Blocks [0,2848): vec8 convert — x->xb (pad to
// 8320 rows), w_qkv->bf16, w_out->bf16. 8-elem-unit boundaries: xb 532480
// (src valid 524800), wqkv 147456, wout 49152; total 729088 = 2848*256.
// Blocks [2848,4896): 3x3 depthwise conv (SAME) + cls passthrough -> locb.
__global__ __launch_bounds__(256) void k_prep(const float* __restrict__ x,
                                              const float* __restrict__ wqkv,
                                              const float* __restrict__ wout,
                                              bf16* __restrict__ xb, bf16* __restrict__ wqkvb,
                                              bf16* __restrict__ woutb,
                                              const float* __restrict__ wdw,
                                              bf16* __restrict__ locb) {
  if (blockIdx.x >= 2848) {
    const int lb = blockIdx.x - 2848;          // 0..2047
    const int b = lb >> 8;
    const int y = (lb >> 3) & 31;
    const int xseg = lb & 7;
    const int c = threadIdx.x * 2;
    const int x0 = xseg * 4;
    const bool hm = (y > 0), hp = (y < 31);
    float wa[9], wb[9];
#pragma unroll
    for (int k = 0; k < 9; ++k) {
      wa[k] = wdw[(size_t)c * 9 + k];
      wb[k] = wdw[(size_t)(c + 1) * 9 + k];
    }
    const float* xrow = x + ((size_t)b * 1025 + 1) * 512 + c;
    float A0 = 0.f, B0 = 0.f, A1 = 0.f, B1 = 0.f;
    for (int cc = x0 - 1; cc <= x0 + 4; ++cc) {
      float2 v0 = make_float2(0.f, 0.f), v1 = v0, v2 = v0;
      if (cc >= 0 && cc < 32) {
        v1 = *(const float2*)&xrow[((size_t)y * 32 + cc) * 512];
        if (hm) v0 = *(const float2*)&xrow[((size_t)(y - 1) * 32 + cc) * 512];
        if (hp) v2 = *(const float2*)&xrow[((size_t)(y + 1) * 32 + cc) * 512];
      }
      float t0a = v0.x * wa[0] + v1.x * wa[3] + v2.x * wa[6];
      float t1a = v0.x * wa[1] + v1.x * wa[4] + v2.x * wa[7];
      float t2a = v0.x * wa[2] + v1.x * wa[5] + v2.x * wa[8];
      float t0b = v0.y * wb[0] + v1.y * wb[3] + v2.y * wb[6];
      float t1b = v0.y * wb[1] + v1.y * wb[4] + v2.y * wb[7];
      float t2b = v0.y * wb[2] + v1.y * wb[5] + v2.y * wb[8];
      int oc = cc - 1;
      if (oc >= x0 && oc <= x0 + 3) {
        size_t o = ((size_t)b * 1025 + 1 + y * 32 + oc) * 512 + c;
        *(uint32_t*)&locb[o] = pk2(A0 + t2a, A1 + t2b);
      }
      A0 = B0 + t1a; B0 = t0a;
      A1 = B1 + t1b; B1 = t0b;
    }
    if (y == 0 && xseg == 0) {
      float2 xc = *(const float2*)&x[((size_t)b * 1025) * 512 + c];
      *(uint32_t*)&locb[((size_t)b * 1025) * 512 + c] = pk2(xc.x, xc.y);
    }
    return;
  }
  // ---- vec8 prep branch (u = 8-elem unit index)
  int u = blockIdx.x * 256 + threadIdx.x;
  const float* src = nullptr;
  bf16* dst = nullptr;
  bool zero = false;
  if (u < 532480) {
    if (u >= 524800) zero = true;
    src = x; dst = xb;
  } else if (u < 679936) {
    u -= 532480; src = wqkv; dst = wqkvb;
  } else {
    u -= 679936; src = wout; dst = woutb;
  }
  float4 a = make_float4(0.f, 0.f, 0.f, 0.f), bq = a;
  if (!zero) {
    a  = *(const float4*)&src[(size_t)u * 8];
    bq = *(const float4*)&src[(size_t)u * 8 + 4];
  }
  uint4 p;
  p.x = pk2(a.x, a.y);
  p.y = pk2(a.z, a.w);
  p.z = pk2(bq.x, bq.y);
  p.w = pk2(bq.z, bq.w);
  *(uint4*)&dst[(size_t)u * 8] = p;
}

// Tiled bf16 GEMM, 3-STAGE pipeline (T3+T4): BK=32, triple-buffered LDS,
// counted vmcnt -> prefetch distance 2. Chunk swizzle (row>>1)&3.
// Bijective XCD-chunked 1D grid (m204).
// TPB=512: 8 waves (2x4 grid, wave tile 64x32). TPB=256: 4 waves (2x2).
// EPI=0 (128x128, NTN=18, TPB=512): q/k blocks (tn<12) use a COALESCED
//   LDS round-trip epilogue (per-head contiguous 16KB regions, 8B stores in
//   128B runs); vP blocks (tn>=12) keep the scattered path.
// EPI=1 (128x64, NTN=8, TPB=256): +bias, fp32 out, row<8200. Grid 520.
template <int EPI, int BM, int BN, int NTN, int TPB>
__global__ __launch_bounds__(TPB) void k_gemm(const bf16* __restrict__ A,
                                              const bf16* __restrict__ Bt, int K,
                                              bf16* __restrict__ q, bf16* __restrict__ kk,
                                              bf16* __restrict__ vt,
                                              const float* __restrict__ bias,
                                              float* __restrict__ out) {
  __shared__ __attribute__((aligned(16))) bf16 smem[3 * (BM + BN) * 32];
  constexpr int NWAVE = TPB / 64;
  constexpr int WCN = (NWAVE == 8) ? 4 : 2;   // wave-grid cols
  constexpr int WRN = NWAVE / WCN;            // wave-grid rows (=2)
  constexpr int WROWS = BM / WRN, WCOLS = BN / WCN;
  constexpr int MF = WROWS / 16, NF = WCOLS / 16;
  constexpr int AL = BM / 16 / NWAVE;         // A wave-loads per stage
  constexpr int BL = BN / 16 / NWAVE;         // B wave-loads per stage
  constexpr int LOADS = AL + BL;
  const int tid = threadIdx.x;
  const int lane = tid & 63;
  const int w = tid >> 6;
  const int wr = w / WCN, wc = w % WCN;
  const int l15 = lane & 15, l4 = lane >> 4;

  auto sAb = [&](int bi) { return smem + bi * (BM * 32); };
  auto sBb = [&](int bi) { return smem + 3 * BM * 32 + bi * (BN * 32); };

  const int nwg = gridDim.x;
  const int qq = nwg >> 3, rr = nwg & 7;
  const int xcd = blockIdx.x & 7, idx = blockIdx.x >> 3;
  const int logical = (xcd < rr) ? xcd * (qq + 1) + idx
                                 : rr * (qq + 1) + (xcd - rr) * qq + idx;
  const int tm = logical / NTN, tn = logical - tm * NTN;

  f32x4 acc[MF][NF] = {};

  const int srow = lane >> 2, schunk = lane & 3;
  const int rA = w * (AL * 16) + srow;
  const bf16* aS = A + ((size_t)(tm * BM + rA)) * K + ((schunk ^ ((rA >> 1) & 3)) * 8);
  const int rB = w * (BL * 16) + srow;
  const bf16* bS = Bt + ((size_t)(tn * BN + rB)) * K + ((schunk ^ ((rB >> 1) & 3)) * 8);

  auto STAGE = [&](int bi, int kt) {
    size_t o = (size_t)kt * 32;
#pragma unroll
    for (int i = 0; i < AL; ++i)
      gload_lds16(aS + (size_t)i * 16 * K + o, &sAb(bi)[(w * (AL * 16) + i * 16) * 32]);
#pragma unroll
    for (int i = 0; i < BL; ++i)
      gload_lds16(bS + (size_t)i * 16 * K + o, &sBb(bi)[(w * (BL * 16) + i * 16) * 32]);
  };

  STAGE(0, 0);
  STAGE(1, 1);
  int cur = 0;
  const int Ksteps = K >> 5;
  for (int kt = 0; kt < Ksteps; ++kt) {
    if (kt + 1 < Ksteps) {
      if constexpr (LOADS == 4)      asm volatile("s_waitcnt vmcnt(4)" ::: "memory");
      else if constexpr (LOADS == 3) asm volatile("s_waitcnt vmcnt(3)" ::: "memory");
      else                           asm volatile("s_waitcnt vmcnt(2)" ::: "memory");
    } else {
      asm volatile("s_waitcnt vmcnt(0)" ::: "memory");
    }
    __builtin_amdgcn_s_barrier();
    __builtin_amdgcn_sched_barrier(0);
    if (kt + 2 < Ksteps) {
      int b2 = cur + 2; if (b2 >= 3) b2 -= 3;
      STAGE(b2, kt + 2);
    }

    const bf16* a_ = sAb(cur);
    const bf16* b_ = sBb(cur);
    bf16x8 af[MF], bfr[NF];
#pragma unroll
    for (int mf = 0; mf < MF; ++mf) {
      int row = wr * WROWS + mf * 16 + l15;
      int phys = l4 ^ ((row >> 1) & 3);
      af[mf] = *(const bf16x8*)&a_[row * 32 + phys * 8];
    }
#pragma unroll
    for (int nf = 0; nf < NF; ++nf) {
      int row = wc * WCOLS + nf * 16 + l15;
      int phys = l4 ^ ((row >> 1) & 3);
      bfr[nf] = *(const bf16x8*)&b_[row * 32 + phys * 8];
    }
    __builtin_amdgcn_s_setprio(1);
#pragma unroll
    for (int mf = 0; mf < MF; ++mf)
#pragma unroll
      for (int nf = 0; nf < NF; ++nf)
        acc[mf][nf] =
            __builtin_amdgcn_mfma_f32_16x16x32_bf16(bfr[nf], af[mf], acc[mf][nf], 0, 0, 0);
    __builtin_amdgcn_s_setprio(0);
    ++cur; if (cur >= 3) cur = 0;
  }

  const int RbaseL = tm * BM + wr * WROWS + l15;
  const int CbaseL = tn * BN + wc * WCOLS + l4 * 4;

  if (EPI == 0 && tn < 12) {
    // ---- coalesced q/k epilogue via LDS round-trip ----
    constexpr int PAD = 132;                  // bf16 elems per row (8B-aligned)
    const int seg = tn / 6;                   // 0 = q, 1 = k (tile fits one seg)
    const float scl = seg ? 1.f : QSCALE;
    bf16* ct = smem;                          // [BM][PAD] C-tile
    __syncthreads();                          // K-loop LDS dead everywhere
#pragma unroll
    for (int mf = 0; mf < MF; ++mf) {
      int rl = wr * WROWS + mf * 16 + l15;
#pragma unroll
      for (int nf = 0; nf < NF; ++nf) {
        int cl = wc * WCOLS + nf * 16 + l4 * 4;
        uint2 p;
        p.x = pk2(acc[mf][nf][0] * scl, acc[mf][nf][1] * scl);
        p.y = pk2(acc[mf][nf][2] * scl, acc[mf][nf][3] * scl);
        *(uint2*)&ct[rl * PAD + cl] = p;
      }
    }
    __syncthreads();
    bf16* dst = seg ? kk : q;
    const int h0 = tn * 2 - seg * 12;         // first of the 2 heads in tile
#pragma unroll
    for (int it = 0; it < BM * 32 / TPB; ++it) {
      int u = it * TPB + tid;                 // 8B unit: 32 per row
      int row = u >> 5;
      int R = tm * BM + row;
      if (R >= 8200) continue;
      int b = R / 1025, n = R - b * 1025;     // per-row -> straddle-safe
      int hh = (u >> 4) & 1;
      int d0 = (u & 15) * 4;
      uint2 v = *(const uint2*)&ct[row * PAD + hh * 64 + d0];
      *(uint2*)&dst[(((size_t)b * 12 + h0 + hh) * 1088 + n) * 64 + d0] = v;
    }
    return;
  }

#pragma unroll
  for (int mf = 0; mf < MF; ++mf) {
    int R = RbaseL + mf * 16;
    if (R >= 8200) continue;
    if (EPI == 0) {
      int b = R / 1025;
      int n = R - b * 1025;
      int kvq = n >> 2, e = n & 3;
#pragma unroll
      for (int nf = 0; nf < NF; ++nf) {
        int Cc0 = CbaseL + nf * 16;
        int inner = Cc0 - 1536;               // tn>=12 -> seg 2 (vP) only
        int h = inner >> 6, d0 = inner & 63;
        bf16* vb = &vt[(((size_t)(b * 12 + h) * 272 + kvq) * 64 + d0) * 4 + e];
#pragma unroll
        for (int r = 0; r < 4; ++r) vb[r * 4] = (bf16)acc[mf][nf][r];
      }
    } else {
#pragma unroll
      for (int nf = 0; nf < NF; ++nf) {
        int Cc0 = CbaseL + nf * 16;
        float4 bz = *(const float4*)&bias[Cc0];
        float4 o4;
        o4.x = acc[mf][nf][0] + bz.x;
        o4.y = acc[mf][nf][1] + bz.y;
        o4.z = acc[mf][nf][2] + bz.z;
        o4.w = acc[mf][nf][3] + bz.w;
        *(float4*)&out[(size_t)R * 512 + Cc0] = o4;
      }
    }
  }
}

// Flash attention, swapped-QK^T, double-buffered K/V, shift-free softmax.
// 8 WAVES per block (512 thr), 128 q-rows/block, grid 864 (= 8*108, exact
// XCD-bijective): 4 blocks/CU x 8 waves = 32 waves/CU, single dispatch round.
// 16 full KV tiles + rank-1 tail. PV via mfma_16x16x16 (P in-register).
// Epilogue fuses the depthwise-conv local branch: adds locb for heads h<8.
// LDS = 32768 B. NOTE: no min-waves launch_bounds (round-4 spill lesson).
__global__ __launch_bounds__(512) void k_flash(const bf16* __restrict__ qg,
                                               const bf16* __restrict__ kg,
                                               const bf16* __restrict__ vpg,
                                               const bf16* __restrict__ locb,
                                               bf16* __restrict__ outb) {
  __shared__ __attribute__((aligned(16))) bf16 sK[2][64 * 64];
  __shared__ __attribute__((aligned(16))) bf16 sVP[2][16 * 256];  // 16 kvq x 64 d x 4 e
  const int tid = threadIdx.x, lane = tid & 63, w = tid >> 6;  // w = 0..7
  const int l15 = lane & 15, l4 = lane >> 4;
  // XCD-contiguous mapping: 864 = 8 * 108
  const int wg = blockIdx.x;
  const int logical = (wg & 7) * 108 + (wg >> 3);
  const int bh = logical / 9, qgp = logical - bh * 9;   // 9 q-groups of 128
  const int b = bh / 12, h = bh - b * 12;

  // Q fragments (pre-scaled by QSCALE in the QKV GEMM epilogue)
  size_t qoff = ((size_t)bh * 1088 + qgp * 128 + w * 16 + l15) * 64 + l4 * 8;
  const bf16x8 qf0 = *(const bf16x8*)&qg[qoff];
  const bf16x8 qf1 = *(const bf16x8*)&qg[qoff + 32];

  float lreg = 0.f;  // per-lane partial row sum (reduced in epilogue)
  f32x4 oa[4] = {};

  const int px0 = (l4 ^ (l15 & 7)) * 8;        // K LDS swizzled chunk, ks=0
  const int px1 = ((4 + l4) ^ (l15 & 7)) * 8;  // ks=1

  // Staging: wave w covers K rows [w*8, w*8+8) (1 gload/wave) and V elements
  // [w*512, (w+1)*512) (1 gload/wave). Both tiles advance 4096 elems per t.
  const int rowK = w * 8 + (lane >> 3);
  const int clogK = (lane & 7) ^ (rowK & 7);
  const bf16* kS = kg + ((size_t)bh * 1088 + rowK) * 64 + clogK * 8;
  const bf16* vS = vpg + (size_t)bh * 69632 + w * 512 + lane * 8;
  const int kD = w * 512;   // wave-uniform LDS elem base (lane adds *8)
  const int vD = w * 512;

  auto STAGE = [&](int bi, int t) {
    size_t o = (size_t)t * 4096;
    gload_lds16(kS + o, &sK[bi][kD]);
    gload_lds16(vS + o, &sVP[bi][vD]);
  };

  STAGE(0, 0);
  int cur = 0;

  for (int t = 0; t < 16; ++t) {
    // Wait this tile's loads (issued one full iteration ago), converge. After
    // the barrier all waves consumed buf[cur^1] -> restage is race-free.
    asm volatile("s_waitcnt vmcnt(0)" ::: "memory");
    __builtin_amdgcn_s_barrier();
    __builtin_amdgcn_sched_barrier(0);
    if (t < 15) STAGE(cur ^ 1, t + 1);

    const bf16* kb_ = sK[cur];
    const bf16* vpb = sVP[cur];

    // S^T = K · Q^T : lane holds S[q=l15][kv = jt*16 + l4*4 + r]
    f32x4 sc[4] = {};
    __builtin_amdgcn_s_setprio(1);
#pragma unroll
    for (int jt = 0; jt < 4; ++jt) {
      bf16x8 a0 = *(const bf16x8*)&kb_[(jt * 16 + l15) * 64 + px0];
      sc[jt] = __builtin_amdgcn_mfma_f32_16x16x32_bf16(a0, qf0, sc[jt], 0, 0, 0);
    }
#pragma unroll
    for (int jt = 0; jt < 4; ++jt) {
      bf16x8 a1 = *(const bf16x8*)&kb_[(jt * 16 + l15) * 64 + px1];
      sc[jt] = __builtin_amdgcn_mfma_f32_16x16x32_bf16(a1, qf1, sc[jt], 0, 0, 0);
    }
    __builtin_amdgcn_s_setprio(0);

    // P = exp2(S); pack per-jt into the 16x16x16 A-fragment directly.
    union { uint32_t u[2]; s4 v; } pa[4];
    float lsum = 0.f;
#pragma unroll
    for (int jt = 0; jt < 4; ++jt) {
      float p0 = fexp2(sc[jt][0]);
      float p1 = fexp2(sc[jt][1]);
      float p2 = fexp2(sc[jt][2]);
      float p3 = fexp2(sc[jt][3]);
      lsum += (p0 + p1) + (p2 + p3);
      pa[jt].u[0] = pk2(p0, p1);
      pa[jt].u[1] = pk2(p2, p3);
    }
    lreg += lsum;

    // O += P · V  (16 x mfma_16x16x16, A = in-register P)
    __builtin_amdgcn_s_setprio(1);
#pragma unroll
    for (int jt = 0; jt < 4; ++jt)
#pragma unroll
      for (int db = 0; db < 4; ++db) {
        s4 vf = *(const s4*)&vpb[((jt * 4 + l4) * 64 + db * 16 + l15) * 4];
        oa[db] = pv_mfma(pa[jt].v, vf, oa[db]);
      }
    __builtin_amdgcn_s_setprio(0);
    cur ^= 1;
  }

  // Rank-1 tail: kv = 1024.
  {
    const bf16* k1 = kg + ((size_t)bh * 1088 + 1024) * 64;
    bf16x8 kA = *(const bf16x8*)&k1[l4 * 8];
    bf16x8 kB = *(const bf16x8*)&k1[32 + l4 * 8];
    float s = 0.f;
#pragma unroll
    for (int e = 0; e < 8; ++e)
      s += (float)qf0[e] * (float)kA[e] + (float)qf1[e] * (float)kB[e];
    s += __shfl_xor(s, 16);
    s += __shfl_xor(s, 32);
    float p = fexp2(s);
    if (l4 == 0) lreg += p;  // count once per q-row (epilogue sums l4 copies)
    float pr[4];
#pragma unroll
    for (int r = 0; r < 4; ++r) pr[r] = __shfl(p, l4 * 4 + r);
    const bf16* v1 = vpg + (size_t)bh * 69632 + 65536;  // kvq=256, e=0
#pragma unroll
    for (int db = 0; db < 4; ++db) {
      float vd = (float)v1[(db * 16 + l15) * 4];
#pragma unroll
      for (int r = 0; r < 4; ++r) oa[db][r] += pr[r] * vd;
    }
  }

  float ls = lreg;
  ls += __shfl_xor(ls, 16);
  ls += __shfl_xor(ls, 32);
  float linv = frcp(ls);
#pragma unroll
  for (int r = 0; r < 4; ++r) {
    float ir = __shfl(linv, l4 * 4 + r);
    int n = qgp * 128 + w * 16 + l4 * 4 + r;
    if (n >= 1025) continue;
#pragma unroll
    for (int db = 0; db < 4; ++db) {
      float v = oa[db][r] * ir;
      if (h < 8)
        v += (float)locb[((size_t)b * 1025 + n) * 512 + h * 64 + db * 16 + l15];
      outb[((size_t)b * 1025 + n) * 768 + h * 64 + db * 16 + l15] = (bf16)v;
    }
  }
}

extern "C" void kernel_launch(void* const* d_in, const int* in_sizes, int n_in,
                              void* d_out, int out_size, void* d_ws, size_t ws_size,
                              hipStream_t stream) {
  const float* x = (const float*)d_in[0];
  const float* w_qkv = (const float*)d_in[1];
  const float* w_dw = (const float*)d_in[2];
  const float* w_out = (const float*)d_in[3];
  const float* b_out = (const float*)d_in[4];
  float* out = (float*)d_out;

  char* ws = (char*)d_ws;
  size_t off = 0;
  auto alloc = [&](size_t bytes) {
    char* p = ws + off;
    off = (off + bytes + 255) & ~(size_t)255;
    return p;
  };
  bf16* xb    = (bf16*)alloc((size_t)8320 * 512 * 2);
  bf16* wqkvb = (bf16*)alloc((size_t)2304 * 512 * 2);
  bf16* woutb = (bf16*)alloc((size_t)512 * 768 * 2);
  bf16* qb    = (bf16*)alloc((size_t)96 * 1088 * 64 * 2);
  bf16* kb    = (bf16*)alloc((size_t)96 * 1088 * 64 * 2);
  bf16* vP    = (bf16*)alloc((size_t)96 * 272 * 64 * 4 * 2);  // 69632 elems/head
  bf16* locb  = (bf16*)alloc((size_t)8 * 1025 * 512 * 2);
  bf16* outb  = (bf16*)alloc((size_t)8320 * 768 * 2);

  // Fused prep (vec8: 2848 blocks) + conv (2048 blocks)
  k_prep<<<4896, 256, 0, stream>>>(x, w_qkv, w_out, xb, wqkvb, woutb, w_dw, locb);
  // 1170 = 65*18 blocks (128x128 tiles, 8 waves), XCD-chunked inside kernel
  k_gemm<0, 128, 128, 18, 512><<<1170, 512, 0, stream>>>(xb, wqkvb, 512, qb, kb, vP,
                                                         nullptr, nullptr);
  k_flash<<<864, 512, 0, stream>>>(qb, kb, vP, locb, outb);
  // 520 = 65*8 blocks (128x64 tiles, 4 waves)
  k_gemm<1, 128, 64, 8, 256><<<520, 256, 0, stream>>>(outb, woutb, 768, nullptr, nullptr,
                                                      nullptr, b_out, out);
}